// Round 7
// baseline (483.298 us; speedup 1.0000x reference)
//
#include <hip/hip_runtime.h>
#include <math.h>

#define NUM_B 1024
#define LW 49
#define CD 384
#define NH 12
#define HD 32
#define SCALE_F 19.595917942265423f   // sqrt(384), faithful to reference

typedef unsigned short u16;
typedef unsigned int u32;
typedef __attribute__((ext_vector_type(8))) short short8;      // 8 bf16
typedef __attribute__((ext_vector_type(8))) _Float16 half8;    // 8 f16
typedef __attribute__((ext_vector_type(4))) float floatx4;

// counted-waitcnt pipeline primitives (T4): barrier WITHOUT vmcnt(0) drain
#define ASM_VMCNT(n) asm volatile("s_waitcnt vmcnt(" #n ")" ::: "memory")
#define ASM_LGKM0()  asm volatile("s_waitcnt lgkmcnt(0)" ::: "memory")
#define BAR()        __builtin_amdgcn_s_barrier()

static __device__ __forceinline__ u16 f2bf(float f) {          // RNE f32->bf16
    unsigned u = __float_as_uint(f);
    u += 0x7fffu + ((u >> 16) & 1u);
    return (u16)(u >> 16);
}
static __device__ __forceinline__ float bf2f(u16 s) {
    return __uint_as_float(((unsigned)s) << 16);
}
static __device__ __forceinline__ u16 f2h_bits(float f) {      // RNE f32->f16 bits
    _Float16 h = (_Float16)f;
    u16 u;
    __builtin_memcpy(&u, &h, 2);
    return u;
}
static __device__ __forceinline__ void gl_lds16(const u16* g, u16* l) {
    __builtin_amdgcn_global_load_lds(
        (const __attribute__((address_space(1))) void*)g,
        (__attribute__((address_space(3))) void*)l, 16, 0, 0);
}

// ---------------------------------------------------------------------------
// Fused prologue (1 launch): x -> bf16 hi/lo; qkv_w -> bf16 hi/lo;
// proj_w -> f16 hi/lo; bm table (bias/mask/pad fused, tn-innermost layout).
// ---------------------------------------------------------------------------
#define X4 4816896     // S/4
#define W4 110592
#define P4 36864
#define BM4 49152
__global__ __launch_bounds__(256) void prep(const float* __restrict__ x,
                                            const float* __restrict__ qkv_w,
                                            const float* __restrict__ proj_w,
                                            const float* __restrict__ rel_bias,
                                            const int* __restrict__ rel_coords,
                                            const int* __restrict__ mask,
                                            u16* __restrict__ xbh, u16* __restrict__ xbl,
                                            u16* __restrict__ wbh, u16* __restrict__ wbl,
                                            u16* __restrict__ pfh, u16* __restrict__ pfl,
                                            float* __restrict__ bm) {
    int idx = blockIdx.x * 256 + threadIdx.x;
    if (idx < X4) {
        float4 v = ((const float4*)x)[idx];
        ushort4 h, l;
        h.x = f2bf(v.x); l.x = f2bf(v.x - bf2f(h.x));
        h.y = f2bf(v.y); l.y = f2bf(v.y - bf2f(h.y));
        h.z = f2bf(v.z); l.z = f2bf(v.z - bf2f(h.z));
        h.w = f2bf(v.w); l.w = f2bf(v.w - bf2f(h.w));
        ((ushort4*)xbh)[idx] = h;
        ((ushort4*)xbl)[idx] = l;
    } else if (idx < X4 + W4) {
        int i = idx - X4;
        float4 v = ((const float4*)qkv_w)[i];
        ushort4 h, l;
        h.x = f2bf(v.x); l.x = f2bf(v.x - bf2f(h.x));
        h.y = f2bf(v.y); l.y = f2bf(v.y - bf2f(h.y));
        h.z = f2bf(v.z); l.z = f2bf(v.z - bf2f(h.z));
        h.w = f2bf(v.w); l.w = f2bf(v.w - bf2f(h.w));
        ((ushort4*)wbh)[i] = h;
        ((ushort4*)wbl)[i] = l;
    } else if (idx < X4 + W4 + P4) {
        int i = idx - (X4 + W4);
        float4 v = ((const float4*)proj_w)[i];
        ushort4 h, l;
        h.x = f2h_bits(v.x); l.x = f2h_bits(v.x - (float)(_Float16)v.x);
        h.y = f2h_bits(v.y); l.y = f2h_bits(v.y - (float)(_Float16)v.y);
        h.z = f2h_bits(v.z); l.z = f2h_bits(v.z - (float)(_Float16)v.z);
        h.w = f2h_bits(v.w); l.w = f2h_bits(v.w - (float)(_Float16)v.w);
        ((ushort4*)pfh)[i] = h;
        ((ushort4*)pfl)[i] = l;
    } else if (idx < X4 + W4 + P4 + BM4) {
        int t = idx - (X4 + W4 + P4);
        float4 o;
        float* op = (float*)&o;
#pragma unroll
        for (int i = 0; i < 4; ++i) {
            int j = t * 4 + i;                 // bm flat index
            int e = j & 63;
            int col = (e & 3) * 16 + (e >> 2); // tn*16 + lc
            int row = (j >> 6) & 63;
            int wh_ = j >> 12;                 // 0..47
            int w = wh_ / NH;
            int h = wh_ - w * NH;
            float val = -1.0e30f;
            if (row < LW && col < LW) {
                int ij = row * LW + col;
                val = mask[w * (LW * LW) + ij] ? -1.0e4f
                                               : rel_bias[rel_coords[ij] * NH + h];
            }
            op[i] = val;
        }
        ((float4*)bm)[t] = o;
    }
}

// ---------------------------------------------------------------------------
// QKV GEMM (split-bf16): hi double-buffered, lo SINGLE-buffered (staged
// just-in-time after barrier-2). LDS 48 KB -> 3 blocks/CU (was 2).
// Queue invariant at top of step t: [hi(t), lo(t), hi(t+1)] -> vmcnt(4)
// drains hi(t)+lo(t), keeps hi(t+1) in flight. Same barrier protocol as the
// verified round-3 structure. q/k (nt<6): 3-term; v: 1-term, hi only.
// XCD-chunked grid (3528 = 441*8), n-tile innermost for A-panel L2 reuse.
// ---------------------------------------------------------------------------
__global__ __launch_bounds__(256) void qkv_gemm(const u16* __restrict__ Ah,
                                                const u16* __restrict__ Al,
                                                const u16* __restrict__ Wh,
                                                const u16* __restrict__ Wl,
                                                u32* __restrict__ qp,
                                                u32* __restrict__ kp,
                                                u16* __restrict__ vp) {
    __shared__ u16 As_h[2][128 * 32];   // 16 KB
    __shared__ u16 Bs_h[2][128 * 32];   // 16 KB
    __shared__ u16 As_l[128 * 32];      //  8 KB (single)
    __shared__ u16 Bs_l[128 * 32];      //  8 KB (single)   total 48 KB
    const int tid = threadIdx.x;
    const int w = tid >> 6;
    const int lane = tid & 63;
    // grid = 3528 = 441*8; XCD-chunked bijection, n-tile innermost
    const int bid = blockIdx.x;
    const int logical = (bid & 7) * 441 + (bid >> 3);
    const int mt = logical / 9;
    const int nt = logical - mt * 9;
    const int m0 = mt * 128;
    const int n0 = nt * 128;
    const bool vblk = (nt >= 6);
    const int quad = lane >> 4;
    const int lc = lane & 15;
    const int wrow = (w >> 1) << 6;
    const int wcol = (w & 1) << 6;
    const int srow = lane >> 2;
    const int sch = (lane & 3) * 8;

    floatx4 acc[4][4];
#pragma unroll
    for (int a = 0; a < 4; ++a)
#pragma unroll
        for (int b = 0; b < 4; ++b) acc[a][b] = (floatx4){0.f, 0.f, 0.f, 0.f};

    auto stage_hi = [&](int buf, int k0) {   // 4 loads
#pragma unroll
        for (int i = 0; i < 2; ++i) {
            const int rb = w * 32 + i * 16;
            gl_lds16(Ah + (size_t)(m0 + rb + srow) * CD + k0 + sch, As_h[buf] + rb * 32);
            gl_lds16(Wh + (size_t)(n0 + rb + srow) * CD + k0 + sch, Bs_h[buf] + rb * 32);
        }
    };
    auto stage_lo = [&](int k0) {            // 4 loads, single buffer
#pragma unroll
        for (int i = 0; i < 2; ++i) {
            const int rb = w * 32 + i * 16;
            gl_lds16(Al + (size_t)(m0 + rb + srow) * CD + k0 + sch, As_l + rb * 32);
            gl_lds16(Wl + (size_t)(n0 + rb + srow) * CD + k0 + sch, Bs_l + rb * 32);
        }
    };

    // prologue: queue = [hi(0), lo(0), hi(1)]
    stage_hi(0, 0);
    if (!vblk) stage_lo(0);
    stage_hi(1, 32);

#pragma unroll
    for (int t = 0; t < 12; ++t) {
        if (t == 11) { ASM_VMCNT(0); } else { ASM_VMCNT(4); }
        BAR();                           // hi(t)+lo(t) landed on all waves
        const int hb = t & 1;
        if (!vblk) {
            short8 af_h[4], af_l[4], bf_h[4], bf_l[4];
#pragma unroll
            for (int tt = 0; tt < 4; ++tt) {
                const int ar = (wrow + tt * 16 + lc) * 32 + quad * 8;
                const int br = (wcol + tt * 16 + lc) * 32 + quad * 8;
                af_h[tt] = *(const short8*)(As_h[hb] + ar);
                af_l[tt] = *(const short8*)(As_l + ar);
                bf_h[tt] = *(const short8*)(Bs_h[hb] + br);
                bf_l[tt] = *(const short8*)(Bs_l + br);
            }
#pragma unroll
            for (int tm = 0; tm < 4; ++tm)
#pragma unroll
                for (int tn = 0; tn < 4; ++tn) {
                    acc[tm][tn] = __builtin_amdgcn_mfma_f32_16x16x32_bf16(af_h[tm], bf_h[tn], acc[tm][tn], 0, 0, 0);
                    acc[tm][tn] = __builtin_amdgcn_mfma_f32_16x16x32_bf16(af_h[tm], bf_l[tn], acc[tm][tn], 0, 0, 0);
                    acc[tm][tn] = __builtin_amdgcn_mfma_f32_16x16x32_bf16(af_l[tm], bf_h[tn], acc[tm][tn], 0, 0, 0);
                }
        } else {
            short8 af_h[4], bf_h[4];
#pragma unroll
            for (int tt = 0; tt < 4; ++tt) {
                af_h[tt] = *(const short8*)(As_h[hb] + (wrow + tt * 16 + lc) * 32 + quad * 8);
                bf_h[tt] = *(const short8*)(Bs_h[hb] + (wcol + tt * 16 + lc) * 32 + quad * 8);
            }
#pragma unroll
            for (int tm = 0; tm < 4; ++tm)
#pragma unroll
                for (int tn = 0; tn < 4; ++tn)
                    acc[tm][tn] = __builtin_amdgcn_mfma_f32_16x16x32_bf16(af_h[tm], bf_h[tn], acc[tm][tn], 0, 0, 0);
        }
        ASM_LGKM0(); BAR();              // all waves' LDS reads of this step done
        // restage: lo(t+1) first (oldest in queue), then hi(t+2)
        if (!vblk && t + 1 < 12) stage_lo((t + 1) * 32);
        if (t + 2 < 12) stage_hi(hb, (t + 2) * 32);
    }

    // epilogue: D col = lane&15, row = quad*4 + reg
#pragma unroll
    for (int tn = 0; tn < 4; ++tn) {
        const int nst = n0 + wcol + tn * 16;
        const int t = nst / CD;
        const int rem = nst - t * CD;
        const int h = rem >> 5;
        const int db = (rem & 31) + lc;
#pragma unroll
        for (int tm = 0; tm < 4; ++tm)
#pragma unroll
            for (int r = 0; r < 4; ++r) {
                const int m = m0 + wrow + tm * 16 + quad * 4 + r;
                const int b = m / LW;
                const int l = m - b * LW;
                const size_t o = ((((size_t)b * NH + h) * LW + l) << 5) + db;
                const float vv = acc[tm][tn][r];
                if (t == 2) {
                    vp[o] = f2h_bits(vv);
                } else {
                    const unsigned bits = __float_as_uint(vv);
                    const unsigned hi_high = bits & 0xffff0000u;
                    const u16 lo = f2bf(vv - __uint_as_float(hi_high));
                    const u32 packed = hi_high | (u32)lo;
                    if (t == 0) qp[o] = packed; else kp[o] = packed;
                }
            }
    }
}

// ---------------------------------------------------------------------------
// Proj GEMM (f16 2-term): A+Wh double-buffered, Wl single-buffered JIT.
// LDS 40 KB -> 4 blocks/CU. Queue at top of t: [hi(t)(4), lo(t)(2),
// hi(t+1)(4)] -> vmcnt(4) drains hi(t)+lo(t). out = A*(Wh+Wl)^T + pb.
// ---------------------------------------------------------------------------
__global__ __launch_bounds__(256) void proj_gemm(const u16* __restrict__ Af,
                                                 const u16* __restrict__ Wfh,
                                                 const u16* __restrict__ Wfl,
                                                 const float* __restrict__ pb,
                                                 float* __restrict__ outF) {
    __shared__ u16 As_f[2][128 * 32];   // 16 KB
    __shared__ u16 Bs_h[2][128 * 32];   // 16 KB
    __shared__ u16 Bs_l[128 * 32];      //  8 KB   total 40 KB
    const int tid = threadIdx.x;
    const int w = tid >> 6;
    const int lane = tid & 63;
    // grid = 1176 = 147*8; XCD-chunked bijection, n-tile innermost
    const int bid = blockIdx.x;
    const int logical = (bid & 7) * 147 + (bid >> 3);
    const int mt = logical / 3;
    const int nt = logical - mt * 3;
    const int m0 = mt * 128;
    const int n0 = nt * 128;
    const int quad = lane >> 4;
    const int lc = lane & 15;
    const int wrow = (w >> 1) << 6;
    const int wcol = (w & 1) << 6;
    const int srow = lane >> 2;
    const int sch = (lane & 3) * 8;

    floatx4 acc[4][4];
#pragma unroll
    for (int a = 0; a < 4; ++a)
#pragma unroll
        for (int b = 0; b < 4; ++b) acc[a][b] = (floatx4){0.f, 0.f, 0.f, 0.f};

    auto stage_hi = [&](int buf, int k0) {   // 4 loads
#pragma unroll
        for (int i = 0; i < 2; ++i) {
            const int rb = w * 32 + i * 16;
            gl_lds16(Af + (size_t)(m0 + rb + srow) * CD + k0 + sch, As_f[buf] + rb * 32);
            gl_lds16(Wfh + (size_t)(n0 + rb + srow) * CD + k0 + sch, Bs_h[buf] + rb * 32);
        }
    };
    auto stage_lo = [&](int k0) {            // 2 loads, single buffer
#pragma unroll
        for (int i = 0; i < 2; ++i) {
            const int rb = w * 32 + i * 16;
            gl_lds16(Wfl + (size_t)(n0 + rb + srow) * CD + k0 + sch, Bs_l + rb * 32);
        }
    };

    stage_hi(0, 0);
    stage_lo(0);
    stage_hi(1, 32);

#pragma unroll
    for (int t = 0; t < 12; ++t) {
        if (t == 11) { ASM_VMCNT(0); } else { ASM_VMCNT(4); }
        BAR();
        const int hb = t & 1;
        half8 af[4], bh[4], bl[4];
#pragma unroll
        for (int tt = 0; tt < 4; ++tt) {
            const int ar = (wrow + tt * 16 + lc) * 32 + quad * 8;
            const int br = (wcol + tt * 16 + lc) * 32 + quad * 8;
            af[tt] = *(const half8*)(As_f[hb] + ar);
            bh[tt] = *(const half8*)(Bs_h[hb] + br);
            bl[tt] = *(const half8*)(Bs_l + br);
        }
#pragma unroll
        for (int tm = 0; tm < 4; ++tm)
#pragma unroll
            for (int tn = 0; tn < 4; ++tn) {
                acc[tm][tn] = __builtin_amdgcn_mfma_f32_16x16x32_f16(af[tm], bh[tn], acc[tm][tn], 0, 0, 0);
                acc[tm][tn] = __builtin_amdgcn_mfma_f32_16x16x32_f16(af[tm], bl[tn], acc[tm][tn], 0, 0, 0);
            }
        ASM_LGKM0(); BAR();
        if (t + 1 < 12) stage_lo((t + 1) * 32);
        if (t + 2 < 12) stage_hi(hb, (t + 2) * 32);
    }

#pragma unroll
    for (int tn = 0; tn < 4; ++tn) {
        const int n = n0 + wcol + tn * 16 + lc;
        const float bias = pb[n];
#pragma unroll
        for (int tm = 0; tm < 4; ++tm)
#pragma unroll
            for (int r = 0; r < 4; ++r) {
                const int m = m0 + wrow + tm * 16 + quad * 4 + r;
                outF[(size_t)m * CD + n] = acc[tm][tn][r] + bias;
            }
    }
}

// ---------------------------------------------------------------------------
// MFMA attention: 1 wave per (b,h). q/k packed u32 (hi|lo bf16) from global;
// S = 3-term split-bf16; in-register softmax with DEFERRED 1/sum (P stored
// unnormalized e<=1 in f16; epilogue multiplies by inv in f32).
// Output: single f16, [m][C] layout for the proj GEMM.
// ---------------------------------------------------------------------------
__global__ __launch_bounds__(64) void attn_mfma(const u32* __restrict__ qp,
                                                const u32* __restrict__ kp,
                                                const u16* __restrict__ vh,
                                                const float* __restrict__ bm,
                                                u16* __restrict__ aof) {
    const int bh = blockIdx.x;
    const int b = bh / NH;
    const int h = bh - b * NH;
    const int lane = threadIdx.x;
    const int quad = lane >> 4;
    const int lc = lane & 15;
    __shared__ u16 Vt[32 * 72];
    __shared__ u16 Ps[64 * 72];

    const size_t base = (size_t)bh * (LW * HD);

    short8 aQh[4], aQl[4], bKh[4], bKl[4];
#pragma unroll
    for (int t = 0; t < 4; ++t) {
        int row = t * 16 + lc; if (row > 48) row = 48;
        const size_t o = base + (size_t)row * HD + quad * 8;
        uint4 q0 = *(const uint4*)(qp + o);
        uint4 q1 = *(const uint4*)(qp + o + 4);
        uint4 k0 = *(const uint4*)(kp + o);
        uint4 k1 = *(const uint4*)(kp + o + 4);
        unsigned qv[8] = {q0.x, q0.y, q0.z, q0.w, q1.x, q1.y, q1.z, q1.w};
        unsigned kv[8] = {k0.x, k0.y, k0.z, k0.w, k1.x, k1.y, k1.z, k1.w};
#pragma unroll
        for (int e = 0; e < 8; ++e) {
            aQh[t][e] = (short)(qv[e] >> 16);
            aQl[t][e] = (short)(qv[e] & 0xffffu);
            bKh[t][e] = (short)(kv[e] >> 16);
            bKl[t][e] = (short)(kv[e] & 0xffffu);
        }
    }
    // stage V^T (f16): Vt[d][j] = v[min(j,48)][d]
#pragma unroll
    for (int it = 0; it < 4; ++it) {
        const int idx = lane + it * 64;
        const int j = idx >> 2;
        const int jc = j > 48 ? 48 : j;
        const int ch = (idx & 3) * 8;
        short8 vv = *(const short8*)(vh + base + (size_t)jc * HD + ch);
#pragma unroll
        for (int e = 0; e < 8; ++e) Vt[(ch + e) * 72 + j] = (u16)vv[e];
    }

    floatx4 acc[4][4];
#pragma unroll
    for (int a = 0; a < 4; ++a)
#pragma unroll
        for (int c = 0; c < 4; ++c) acc[a][c] = (floatx4){0.f, 0.f, 0.f, 0.f};
#pragma unroll
    for (int tm = 0; tm < 4; ++tm)
#pragma unroll
        for (int tn = 0; tn < 4; ++tn) {
            acc[tm][tn] = __builtin_amdgcn_mfma_f32_16x16x32_bf16(aQh[tm], bKh[tn], acc[tm][tn], 0, 0, 0);
            acc[tm][tn] = __builtin_amdgcn_mfma_f32_16x16x32_bf16(aQh[tm], bKl[tn], acc[tm][tn], 0, 0, 0);
            acc[tm][tn] = __builtin_amdgcn_mfma_f32_16x16x32_bf16(aQl[tm], bKh[tn], acc[tm][tn], 0, 0, 0);
        }

    float inv_a[16];   // per-(tm,r) 1/sum, fully unrolled static indexing
    const float* bmp = bm + (((size_t)(b & 3) * NH + h) << 12);
#pragma unroll
    for (int tm = 0; tm < 4; ++tm)
#pragma unroll
        for (int r = 0; r < 4; ++r) {
            const int row = tm * 16 + quad * 4 + r;
            const float4 bv = *(const float4*)(bmp + row * 64 + lc * 4);
            const float s0 = fmaf(acc[tm][0][r], SCALE_F, bv.x);
            const float s1 = fmaf(acc[tm][1][r], SCALE_F, bv.y);
            const float s2 = fmaf(acc[tm][2][r], SCALE_F, bv.z);
            const float s3 = fmaf(acc[tm][3][r], SCALE_F, bv.w);
            float mx = fmaxf(fmaxf(s0, s1), fmaxf(s2, s3));
#pragma unroll
            for (int off = 1; off < 16; off <<= 1) mx = fmaxf(mx, __shfl_xor(mx, off));
            const float e0 = __expf(s0 - mx);
            const float e1 = __expf(s1 - mx);
            const float e2 = __expf(s2 - mx);
            const float e3 = __expf(s3 - mx);
            float sum = (e0 + e1) + (e2 + e3);
#pragma unroll
            for (int off = 1; off < 16; off <<= 1) sum += __shfl_xor(sum, off);
            inv_a[tm * 4 + r] = __builtin_amdgcn_rcpf(sum);
            Ps[row * 72 +  0 + lc] = f2h_bits(e0);
            Ps[row * 72 + 16 + lc] = f2h_bits(e1);
            Ps[row * 72 + 32 + lc] = f2h_bits(e2);
            Ps[row * 72 + 48 + lc] = f2h_bits(e3);
        }

    __syncthreads();

    floatx4 o[4][2];
#pragma unroll
    for (int a = 0; a < 4; ++a) { o[a][0] = (floatx4){0.f,0.f,0.f,0.f}; o[a][1] = (floatx4){0.f,0.f,0.f,0.f}; }
#pragma unroll
    for (int ks = 0; ks < 2; ++ks) {
        const half8 bV0 = *(const half8*)(Vt + (lc) * 72 + ks * 32 + quad * 8);
        const half8 bV1 = *(const half8*)(Vt + (16 + lc) * 72 + ks * 32 + quad * 8);
#pragma unroll
        for (int tm = 0; tm < 4; ++tm) {
            const half8 aP = *(const half8*)(Ps + (tm * 16 + lc) * 72 + ks * 32 + quad * 8);
            o[tm][0] = __builtin_amdgcn_mfma_f32_16x16x32_f16(aP, bV0, o[tm][0], 0, 0, 0);
            o[tm][1] = __builtin_amdgcn_mfma_f32_16x16x32_f16(aP, bV1, o[tm][1], 0, 0, 0);
        }
    }
#pragma unroll
    for (int tm = 0; tm < 4; ++tm)
#pragma unroll
        for (int r = 0; r < 4; ++r) {
            const int i = tm * 16 + quad * 4 + r;
            if (i < LW) {
                const float inv = inv_a[tm * 4 + r];
#pragma unroll
                for (int tn = 0; tn < 2; ++tn) {
                    const size_t mm = ((size_t)b * LW + i) * CD + h * HD + tn * 16 + lc;
                    aof[mm] = f2h_bits(o[tm][tn][r] * inv);
                }
            }
        }
}

// ---------------------------------------------------------------------------
extern "C" void kernel_launch(void* const* d_in, const int* in_sizes, int n_in,
                              void* d_out, int out_size, void* d_ws, size_t ws_size,
                              hipStream_t stream) {
    const float* x          = (const float*)d_in[0];
    const int*   mask       = (const int*)d_in[1];
    const float* qkv_w      = (const float*)d_in[2];
    const float* proj_w     = (const float*)d_in[3];
    const float* proj_b     = (const float*)d_in[4];
    const float* rel_bias   = (const float*)d_in[5];
    const int*   rel_coords = (const int*)d_in[6];
    float* out = (float*)d_out;

    const size_t S = (size_t)NUM_B * NH * LW * HD;   // 19,267,584
    // ws (u16 units): xbh S | xbl S | kp 2S | vh S | wbh/wbl | pfh/pfl | bm
    u16* xbh = (u16*)d_ws;
    u16* xbl = xbh + S;
    u32* kp  = (u32*)(xbl + S);           // S u32
    u16* vh  = (u16*)(kp + S);            // S u16
    u16* wbh = vh + S;                    // 442368
    u16* wbl = wbh + 442368;
    u16* pfh = wbl + 442368;              // 147456
    u16* pfl = pfh + 147456;
    float* bm = (float*)(pfl + 147456);   // 196608 floats
    // q packed lives in d_out (S u32 == out_size f32); dead before proj writes
    u32* qp = (u32*)d_out;
    // attn f16 output reuses xbh (x dead after qkv_gemm)
    u16* aof = xbh;

    prep<<<dim3(19584), dim3(256), 0, stream>>>(x, qkv_w, proj_w, rel_bias, rel_coords,
                                                mask, xbh, xbl, wbh, wbl, pfh, pfl, bm);
    qkv_gemm<<<dim3(3528), dim3(256), 0, stream>>>(xbh, xbl, wbh, wbl, qp, kp, vh);
    attn_mfma<<<dim3(NUM_B * NH), dim3(64), 0, stream>>>(qp, kp, vh, bm, aof);
    proj_gemm<<<dim3(1176), dim3(256), 0, stream>>>(aof, pfh, pfl, proj_b, out);
}

// Round 8
// 386.796 us; speedup vs baseline: 1.2495x; 1.2495x over previous
//
#include <hip/hip_runtime.h>
#include <math.h>

#define NUM_B 1024
#define LW 49
#define CD 384
#define NH 12
#define HD 32
#define SCALE_F 19.595917942265423f   // sqrt(384), faithful to reference

typedef unsigned short u16;
typedef unsigned int u32;
typedef __attribute__((ext_vector_type(8))) short short8;      // 8 bf16
typedef __attribute__((ext_vector_type(8))) _Float16 half8;    // 8 f16
typedef __attribute__((ext_vector_type(4))) float floatx4;

// counted-waitcnt pipeline primitives (T4): barrier WITHOUT vmcnt(0) drain
#define ASM_VMCNT(n) asm volatile("s_waitcnt vmcnt(" #n ")" ::: "memory")
#define ASM_LGKM0()  asm volatile("s_waitcnt lgkmcnt(0)" ::: "memory")
#define BAR()        __builtin_amdgcn_s_barrier()

static __device__ __forceinline__ u16 f2bf(float f) {          // RNE f32->bf16
    unsigned u = __float_as_uint(f);
    u += 0x7fffu + ((u >> 16) & 1u);
    return (u16)(u >> 16);
}
static __device__ __forceinline__ float bf2f(u16 s) {
    return __uint_as_float(((unsigned)s) << 16);
}
static __device__ __forceinline__ u16 f2h_bits(float f) {      // RNE f32->f16 bits
    _Float16 h = (_Float16)f;
    u16 u;
    __builtin_memcpy(&u, &h, 2);
    return u;
}
static __device__ __forceinline__ void gl_lds16(const u16* g, u16* l) {
    __builtin_amdgcn_global_load_lds(
        (const __attribute__((address_space(1))) void*)g,
        (__attribute__((address_space(3))) void*)l, 16, 0, 0);
}

// ---------------------------------------------------------------------------
// Fused prologue (1 launch): x -> bf16 hi/lo; qkv_w -> bf16 hi/lo;
// proj_w -> f16 hi/lo; bm table (bias/mask/pad fused, tn-innermost layout).
// ---------------------------------------------------------------------------
#define X4 4816896     // S/4
#define W4 110592
#define P4 36864
#define BM4 49152
__global__ __launch_bounds__(256) void prep(const float* __restrict__ x,
                                            const float* __restrict__ qkv_w,
                                            const float* __restrict__ proj_w,
                                            const float* __restrict__ rel_bias,
                                            const int* __restrict__ rel_coords,
                                            const int* __restrict__ mask,
                                            u16* __restrict__ xbh, u16* __restrict__ xbl,
                                            u16* __restrict__ wbh, u16* __restrict__ wbl,
                                            u16* __restrict__ pfh, u16* __restrict__ pfl,
                                            float* __restrict__ bm) {
    int idx = blockIdx.x * 256 + threadIdx.x;
    if (idx < X4) {
        float4 v = ((const float4*)x)[idx];
        ushort4 h, l;
        h.x = f2bf(v.x); l.x = f2bf(v.x - bf2f(h.x));
        h.y = f2bf(v.y); l.y = f2bf(v.y - bf2f(h.y));
        h.z = f2bf(v.z); l.z = f2bf(v.z - bf2f(h.z));
        h.w = f2bf(v.w); l.w = f2bf(v.w - bf2f(h.w));
        ((ushort4*)xbh)[idx] = h;
        ((ushort4*)xbl)[idx] = l;
    } else if (idx < X4 + W4) {
        int i = idx - X4;
        float4 v = ((const float4*)qkv_w)[i];
        ushort4 h, l;
        h.x = f2bf(v.x); l.x = f2bf(v.x - bf2f(h.x));
        h.y = f2bf(v.y); l.y = f2bf(v.y - bf2f(h.y));
        h.z = f2bf(v.z); l.z = f2bf(v.z - bf2f(h.z));
        h.w = f2bf(v.w); l.w = f2bf(v.w - bf2f(h.w));
        ((ushort4*)wbh)[i] = h;
        ((ushort4*)wbl)[i] = l;
    } else if (idx < X4 + W4 + P4) {
        int i = idx - (X4 + W4);
        float4 v = ((const float4*)proj_w)[i];
        ushort4 h, l;
        h.x = f2h_bits(v.x); l.x = f2h_bits(v.x - (float)(_Float16)v.x);
        h.y = f2h_bits(v.y); l.y = f2h_bits(v.y - (float)(_Float16)v.y);
        h.z = f2h_bits(v.z); l.z = f2h_bits(v.z - (float)(_Float16)v.z);
        h.w = f2h_bits(v.w); l.w = f2h_bits(v.w - (float)(_Float16)v.w);
        ((ushort4*)pfh)[i] = h;
        ((ushort4*)pfl)[i] = l;
    } else if (idx < X4 + W4 + P4 + BM4) {
        int t = idx - (X4 + W4 + P4);
        float4 o;
        float* op = (float*)&o;
#pragma unroll
        for (int i = 0; i < 4; ++i) {
            int j = t * 4 + i;                 // bm flat index
            int e = j & 63;
            int col = (e & 3) * 16 + (e >> 2); // tn*16 + lc
            int row = (j >> 6) & 63;
            int wh_ = j >> 12;                 // 0..47
            int w = wh_ / NH;
            int h = wh_ - w * NH;
            float val = -1.0e30f;
            if (row < LW && col < LW) {
                int ij = row * LW + col;
                val = mask[w * (LW * LW) + ij] ? -1.0e4f
                                               : rel_bias[rel_coords[ij] * NH + h];
            }
            op[i] = val;
        }
        ((float4*)bm)[t] = o;
    }
}

// ---------------------------------------------------------------------------
// QKV GEMM (split-bf16): round-3 verified structure (2-deep dbuf LDS,
// counted vmcnt, 2 barriers/K-step) — measured 163 us. Loads stay in flight
// across barriers; vmcnt never drains to 0 mid-loop. q/k tiles (nt<6):
// 8 loads/stage, 3-term MFMA; v tiles: 4 loads, 1-term.
// XCD-chunked grid (3528 = 441*8), n-tile innermost (A-panel L2 reuse).
// ---------------------------------------------------------------------------
__global__ __launch_bounds__(256) void qkv_gemm(const u16* __restrict__ Ah,
                                                const u16* __restrict__ Al,
                                                const u16* __restrict__ Wh,
                                                const u16* __restrict__ Wl,
                                                u32* __restrict__ qp,
                                                u32* __restrict__ kp,
                                                u16* __restrict__ vp) {
    __shared__ u16 As_h[2][128 * 32];
    __shared__ u16 As_l[2][128 * 32];
    __shared__ u16 Bs_h[2][128 * 32];
    __shared__ u16 Bs_l[2][128 * 32];
    const int tid = threadIdx.x;
    const int w = tid >> 6;
    const int lane = tid & 63;
    // grid = 3528 = 441*8; XCD-chunked bijection, n-tile innermost
    const int bid = blockIdx.x;
    const int logical = (bid & 7) * 441 + (bid >> 3);
    const int mt = logical / 9;
    const int nt = logical - mt * 9;
    const int m0 = mt * 128;
    const int n0 = nt * 128;
    const bool vblk = (nt >= 6);
    const int quad = lane >> 4;
    const int lc = lane & 15;
    const int wrow = (w >> 1) << 6;
    const int wcol = (w & 1) << 6;
    const int srow = lane >> 2;
    const int sch = (lane & 3) * 8;

    floatx4 acc[4][4];
#pragma unroll
    for (int a = 0; a < 4; ++a)
#pragma unroll
        for (int b = 0; b < 4; ++b) acc[a][b] = (floatx4){0.f, 0.f, 0.f, 0.f};

    auto stage = [&](int buf, int k0) {   // q/k: 8 loads; v: 4 loads
#pragma unroll
        for (int i = 0; i < 2; ++i) {
            const int rb = w * 32 + i * 16;
            const size_t ga = (size_t)(m0 + rb + srow) * CD + k0 + sch;
            const size_t gb = (size_t)(n0 + rb + srow) * CD + k0 + sch;
            const int lof = rb * 32;
            gl_lds16(Ah + ga, As_h[buf] + lof);
            gl_lds16(Wh + gb, Bs_h[buf] + lof);
            if (!vblk) {
                gl_lds16(Al + ga, As_l[buf] + lof);
                gl_lds16(Wl + gb, Bs_l[buf] + lof);
            }
        }
    };

    auto compute = [&](int buf) {
        if (!vblk) {
            short8 af_h[4], af_l[4], bf_h[4], bf_l[4];
#pragma unroll
            for (int t = 0; t < 4; ++t) {
                const int ar = (wrow + t * 16 + lc) * 32 + quad * 8;
                af_h[t] = *(const short8*)(As_h[buf] + ar);
                af_l[t] = *(const short8*)(As_l[buf] + ar);
                const int br = (wcol + t * 16 + lc) * 32 + quad * 8;
                bf_h[t] = *(const short8*)(Bs_h[buf] + br);
                bf_l[t] = *(const short8*)(Bs_l[buf] + br);
            }
#pragma unroll
            for (int tm = 0; tm < 4; ++tm)
#pragma unroll
                for (int tn = 0; tn < 4; ++tn) {
                    acc[tm][tn] = __builtin_amdgcn_mfma_f32_16x16x32_bf16(af_h[tm], bf_h[tn], acc[tm][tn], 0, 0, 0);
                    acc[tm][tn] = __builtin_amdgcn_mfma_f32_16x16x32_bf16(af_h[tm], bf_l[tn], acc[tm][tn], 0, 0, 0);
                    acc[tm][tn] = __builtin_amdgcn_mfma_f32_16x16x32_bf16(af_l[tm], bf_h[tn], acc[tm][tn], 0, 0, 0);
                }
        } else {
            short8 af_h[4], bf_h[4];
#pragma unroll
            for (int t = 0; t < 4; ++t) {
                af_h[t] = *(const short8*)(As_h[buf] + (wrow + t * 16 + lc) * 32 + quad * 8);
                bf_h[t] = *(const short8*)(Bs_h[buf] + (wcol + t * 16 + lc) * 32 + quad * 8);
            }
#pragma unroll
            for (int tm = 0; tm < 4; ++tm)
#pragma unroll
                for (int tn = 0; tn < 4; ++tn)
                    acc[tm][tn] = __builtin_amdgcn_mfma_f32_16x16x32_bf16(af_h[tm], bf_h[tn], acc[tm][tn], 0, 0, 0);
        }
    };

    stage(0, 0);
    stage(1, 32);
    if (!vblk) {
#pragma unroll
        for (int t = 0; t < 12; t += 2) {
            ASM_VMCNT(8); BAR();
            compute(0);
            ASM_LGKM0(); BAR();
            if (t + 2 < 12) { stage(0, (t + 2) * 32); ASM_VMCNT(8); }
            else            { ASM_VMCNT(0); }
            BAR();
            compute(1);
            ASM_LGKM0(); BAR();
            if (t + 2 < 12) stage(1, (t + 3) * 32);
        }
    } else {
#pragma unroll
        for (int t = 0; t < 12; t += 2) {
            ASM_VMCNT(4); BAR();
            compute(0);
            ASM_LGKM0(); BAR();
            if (t + 2 < 12) { stage(0, (t + 2) * 32); ASM_VMCNT(4); }
            else            { ASM_VMCNT(0); }
            BAR();
            compute(1);
            ASM_LGKM0(); BAR();
            if (t + 2 < 12) stage(1, (t + 3) * 32);
        }
    }

    // epilogue: D col = lane&15, row = quad*4 + reg
#pragma unroll
    for (int tn = 0; tn < 4; ++tn) {
        const int nst = n0 + wcol + tn * 16;
        const int t = nst / CD;
        const int rem = nst - t * CD;
        const int h = rem >> 5;
        const int db = (rem & 31) + lc;
#pragma unroll
        for (int tm = 0; tm < 4; ++tm)
#pragma unroll
            for (int r = 0; r < 4; ++r) {
                const int m = m0 + wrow + tm * 16 + quad * 4 + r;
                const int b = m / LW;
                const int l = m - b * LW;
                const size_t o = ((((size_t)b * NH + h) * LW + l) << 5) + db;
                const float vv = acc[tm][tn][r];
                if (t == 2) {
                    vp[o] = f2h_bits(vv);
                } else {
                    const unsigned bits = __float_as_uint(vv);
                    const unsigned hi_high = bits & 0xffff0000u;
                    const u16 lo = f2bf(vv - __uint_as_float(hi_high));
                    const u32 packed = hi_high | (u32)lo;
                    if (t == 0) qp[o] = packed; else kp[o] = packed;
                }
            }
    }
}

// ---------------------------------------------------------------------------
// Proj GEMM (f16 2-term): round-3 verified structure (dbuf + counted vmcnt).
// out[m][n] = sum_k A[m][k]*(Wh+Wl)[n][k] + pb[n].
// ---------------------------------------------------------------------------
__global__ __launch_bounds__(256) void proj_gemm(const u16* __restrict__ Af,
                                                 const u16* __restrict__ Wfh,
                                                 const u16* __restrict__ Wfl,
                                                 const float* __restrict__ pb,
                                                 float* __restrict__ outF) {
    __shared__ u16 As_f[2][128 * 32];
    __shared__ u16 Bs_h[2][128 * 32];
    __shared__ u16 Bs_l[2][128 * 32];
    const int tid = threadIdx.x;
    const int w = tid >> 6;
    const int lane = tid & 63;
    // grid = 1176 = 147*8; XCD-chunked bijection, n-tile innermost
    const int bid = blockIdx.x;
    const int logical = (bid & 7) * 147 + (bid >> 3);
    const int mt = logical / 3;
    const int nt = logical - mt * 3;
    const int m0 = mt * 128;
    const int n0 = nt * 128;
    const int quad = lane >> 4;
    const int lc = lane & 15;
    const int wrow = (w >> 1) << 6;
    const int wcol = (w & 1) << 6;
    const int srow = lane >> 2;
    const int sch = (lane & 3) * 8;

    floatx4 acc[4][4];
#pragma unroll
    for (int a = 0; a < 4; ++a)
#pragma unroll
        for (int b = 0; b < 4; ++b) acc[a][b] = (floatx4){0.f, 0.f, 0.f, 0.f};

    auto stage = [&](int buf, int k0) {   // 6 loads
#pragma unroll
        for (int i = 0; i < 2; ++i) {
            const int rb = w * 32 + i * 16;
            const size_t ga = (size_t)(m0 + rb + srow) * CD + k0 + sch;
            const size_t gb = (size_t)(n0 + rb + srow) * CD + k0 + sch;
            const int lof = rb * 32;
            gl_lds16(Af + ga, As_f[buf] + lof);
            gl_lds16(Wfh + gb, Bs_h[buf] + lof);
            gl_lds16(Wfl + gb, Bs_l[buf] + lof);
        }
    };

    auto compute = [&](int buf) {
        half8 af[4], bh[4], bl[4];
#pragma unroll
        for (int t = 0; t < 4; ++t) {
            af[t] = *(const half8*)(As_f[buf] + (wrow + t * 16 + lc) * 32 + quad * 8);
            const int br = (wcol + t * 16 + lc) * 32 + quad * 8;
            bh[t] = *(const half8*)(Bs_h[buf] + br);
            bl[t] = *(const half8*)(Bs_l[buf] + br);
        }
#pragma unroll
        for (int tm = 0; tm < 4; ++tm)
#pragma unroll
            for (int tn = 0; tn < 4; ++tn) {
                acc[tm][tn] = __builtin_amdgcn_mfma_f32_16x16x32_f16(af[tm], bh[tn], acc[tm][tn], 0, 0, 0);
                acc[tm][tn] = __builtin_amdgcn_mfma_f32_16x16x32_f16(af[tm], bl[tn], acc[tm][tn], 0, 0, 0);
            }
    };

    stage(0, 0);
    stage(1, 32);
#pragma unroll
    for (int t = 0; t < 12; t += 2) {
        ASM_VMCNT(6); BAR();
        compute(0);
        ASM_LGKM0(); BAR();
        if (t + 2 < 12) { stage(0, (t + 2) * 32); ASM_VMCNT(6); }
        else            { ASM_VMCNT(0); }
        BAR();
        compute(1);
        ASM_LGKM0(); BAR();
        if (t + 2 < 12) stage(1, (t + 3) * 32);
    }

#pragma unroll
    for (int tn = 0; tn < 4; ++tn) {
        const int n = n0 + wcol + tn * 16 + lc;
        const float bias = pb[n];
#pragma unroll
        for (int tm = 0; tm < 4; ++tm)
#pragma unroll
            for (int r = 0; r < 4; ++r) {
                const int m = m0 + wrow + tm * 16 + quad * 4 + r;
                outF[(size_t)m * CD + n] = acc[tm][tn][r] + bias;
            }
    }
}

// ---------------------------------------------------------------------------
// MFMA attention: 1 wave per (b,h). q/k packed u32 (hi|lo bf16) from global;
// S = 3-term split-bf16; in-register softmax with DEFERRED 1/sum (P stored
// unnormalized e<=1 in f16; epilogue multiplies by inv in f32).
// Output: single f16, [m][C] layout for the proj GEMM.
// ---------------------------------------------------------------------------
__global__ __launch_bounds__(64) void attn_mfma(const u32* __restrict__ qp,
                                                const u32* __restrict__ kp,
                                                const u16* __restrict__ vh,
                                                const float* __restrict__ bm,
                                                u16* __restrict__ aof) {
    const int bh = blockIdx.x;
    const int b = bh / NH;
    const int h = bh - b * NH;
    const int lane = threadIdx.x;
    const int quad = lane >> 4;
    const int lc = lane & 15;
    __shared__ u16 Vt[32 * 72];
    __shared__ u16 Ps[64 * 72];

    const size_t base = (size_t)bh * (LW * HD);

    short8 aQh[4], aQl[4], bKh[4], bKl[4];
#pragma unroll
    for (int t = 0; t < 4; ++t) {
        int row = t * 16 + lc; if (row > 48) row = 48;
        const size_t o = base + (size_t)row * HD + quad * 8;
        uint4 q0 = *(const uint4*)(qp + o);
        uint4 q1 = *(const uint4*)(qp + o + 4);
        uint4 k0 = *(const uint4*)(kp + o);
        uint4 k1 = *(const uint4*)(kp + o + 4);
        unsigned qv[8] = {q0.x, q0.y, q0.z, q0.w, q1.x, q1.y, q1.z, q1.w};
        unsigned kv[8] = {k0.x, k0.y, k0.z, k0.w, k1.x, k1.y, k1.z, k1.w};
#pragma unroll
        for (int e = 0; e < 8; ++e) {
            aQh[t][e] = (short)(qv[e] >> 16);
            aQl[t][e] = (short)(qv[e] & 0xffffu);
            bKh[t][e] = (short)(kv[e] >> 16);
            bKl[t][e] = (short)(kv[e] & 0xffffu);
        }
    }
    // stage V^T (f16): Vt[d][j] = v[min(j,48)][d]
#pragma unroll
    for (int it = 0; it < 4; ++it) {
        const int idx = lane + it * 64;
        const int j = idx >> 2;
        const int jc = j > 48 ? 48 : j;
        const int ch = (idx & 3) * 8;
        short8 vv = *(const short8*)(vh + base + (size_t)jc * HD + ch);
#pragma unroll
        for (int e = 0; e < 8; ++e) Vt[(ch + e) * 72 + j] = (u16)vv[e];
    }

    floatx4 acc[4][4];
#pragma unroll
    for (int a = 0; a < 4; ++a)
#pragma unroll
        for (int c = 0; c < 4; ++c) acc[a][c] = (floatx4){0.f, 0.f, 0.f, 0.f};
#pragma unroll
    for (int tm = 0; tm < 4; ++tm)
#pragma unroll
        for (int tn = 0; tn < 4; ++tn) {
            acc[tm][tn] = __builtin_amdgcn_mfma_f32_16x16x32_bf16(aQh[tm], bKh[tn], acc[tm][tn], 0, 0, 0);
            acc[tm][tn] = __builtin_amdgcn_mfma_f32_16x16x32_bf16(aQh[tm], bKl[tn], acc[tm][tn], 0, 0, 0);
            acc[tm][tn] = __builtin_amdgcn_mfma_f32_16x16x32_bf16(aQl[tm], bKh[tn], acc[tm][tn], 0, 0, 0);
        }

    float inv_a[16];   // per-(tm,r) 1/sum, fully unrolled static indexing
    const float* bmp = bm + (((size_t)(b & 3) * NH + h) << 12);
#pragma unroll
    for (int tm = 0; tm < 4; ++tm)
#pragma unroll
        for (int r = 0; r < 4; ++r) {
            const int row = tm * 16 + quad * 4 + r;
            const float4 bv = *(const float4*)(bmp + row * 64 + lc * 4);
            const float s0 = fmaf(acc[tm][0][r], SCALE_F, bv.x);
            const float s1 = fmaf(acc[tm][1][r], SCALE_F, bv.y);
            const float s2 = fmaf(acc[tm][2][r], SCALE_F, bv.z);
            const float s3 = fmaf(acc[tm][3][r], SCALE_F, bv.w);
            float mx = fmaxf(fmaxf(s0, s1), fmaxf(s2, s3));
#pragma unroll
            for (int off = 1; off < 16; off <<= 1) mx = fmaxf(mx, __shfl_xor(mx, off));
            const float e0 = __expf(s0 - mx);
            const float e1 = __expf(s1 - mx);
            const float e2 = __expf(s2 - mx);
            const float e3 = __expf(s3 - mx);
            float sum = (e0 + e1) + (e2 + e3);
#pragma unroll
            for (int off = 1; off < 16; off <<= 1) sum += __shfl_xor(sum, off);
            inv_a[tm * 4 + r] = __builtin_amdgcn_rcpf(sum);
            Ps[row * 72 +  0 + lc] = f2h_bits(e0);
            Ps[row * 72 + 16 + lc] = f2h_bits(e1);
            Ps[row * 72 + 32 + lc] = f2h_bits(e2);
            Ps[row * 72 + 48 + lc] = f2h_bits(e3);
        }

    __syncthreads();

    floatx4 o[4][2];
#pragma unroll
    for (int a = 0; a < 4; ++a) { o[a][0] = (floatx4){0.f,0.f,0.f,0.f}; o[a][1] = (floatx4){0.f,0.f,0.f,0.f}; }
#pragma unroll
    for (int ks = 0; ks < 2; ++ks) {
        const half8 bV0 = *(const half8*)(Vt + (lc) * 72 + ks * 32 + quad * 8);
        const half8 bV1 = *(const half8*)(Vt + (16 + lc) * 72 + ks * 32 + quad * 8);
#pragma unroll
        for (int tm = 0; tm < 4; ++tm) {
            const half8 aP = *(const half8*)(Ps + (tm * 16 + lc) * 72 + ks * 32 + quad * 8);
            o[tm][0] = __builtin_amdgcn_mfma_f32_16x16x32_f16(aP, bV0, o[tm][0], 0, 0, 0);
            o[tm][1] = __builtin_amdgcn_mfma_f32_16x16x32_f16(aP, bV1, o[tm][1], 0, 0, 0);
        }
    }
#pragma unroll
    for (int tm = 0; tm < 4; ++tm)
#pragma unroll
        for (int r = 0; r < 4; ++r) {
            const int i = tm * 16 + quad * 4 + r;
            if (i < LW) {
                const float inv = inv_a[tm * 4 + r];
#pragma unroll
                for (int tn = 0; tn < 2; ++tn) {
                    const size_t mm = ((size_t)b * LW + i) * CD + h * HD + tn * 16 + lc;
                    aof[mm] = f2h_bits(o[tm][tn][r] * inv);
                }
            }
        }
}

// ---------------------------------------------------------------------------
extern "C" void kernel_launch(void* const* d_in, const int* in_sizes, int n_in,
                              void* d_out, int out_size, void* d_ws, size_t ws_size,
                              hipStream_t stream) {
    const float* x          = (const float*)d_in[0];
    const int*   mask       = (const int*)d_in[1];
    const float* qkv_w      = (const float*)d_in[2];
    const float* proj_w     = (const float*)d_in[3];
    const float* proj_b     = (const float*)d_in[4];
    const float* rel_bias   = (const float*)d_in[5];
    const int*   rel_coords = (const int*)d_in[6];
    float* out = (float*)d_out;

    const size_t S = (size_t)NUM_B * NH * LW * HD;   // 19,267,584
    // ws (u16 units): xbh S | xbl S | kp 2S | vh S | wbh/wbl | pfh/pfl | bm
    u16* xbh = (u16*)d_ws;
    u16* xbl = xbh + S;
    u32* kp  = (u32*)(xbl + S);           // S u32
    u16* vh  = (u16*)(kp + S);            // S u16
    u16* wbh = vh + S;                    // 442368
    u16* wbl = wbh + 442368;
    u16* pfh = wbl + 442368;              // 147456
    u16* pfl = pfh + 147456;
    float* bm = (float*)(pfl + 147456);   // 196608 floats
    // q packed lives in d_out (S u32 == out_size f32); dead before proj writes
    u32* qp = (u32*)d_out;
    // attn f16 output reuses xbh (x dead after qkv_gemm)
    u16* aof = xbh;

    prep<<<dim3(19584), dim3(256), 0, stream>>>(x, qkv_w, proj_w, rel_bias, rel_coords,
                                                mask, xbh, xbl, wbh, wbl, pfh, pfl, bm);
    qkv_gemm<<<dim3(3528), dim3(256), 0, stream>>>(xbh, xbl, wbh, wbl, qp, kp, vh);
    attn_mfma<<<dim3(NUM_B * NH), dim3(64), 0, stream>>>(qp, kp, vh, bm, aof);
    proj_gemm<<<dim3(1176), dim3(256), 0, stream>>>(aof, pfh, pfl, proj_b, out);
}

// Round 9
// 377.271 us; speedup vs baseline: 1.2810x; 1.0252x over previous
//
#include <hip/hip_runtime.h>
#include <math.h>

#define NUM_B 1024
#define LW 49
#define CD 384
#define NH 12
#define HD 32
#define SCALE_F 19.595917942265423f   // sqrt(384), faithful to reference

typedef unsigned short u16;
typedef unsigned int u32;
typedef __attribute__((ext_vector_type(8))) short short8;      // 8 bf16
typedef __attribute__((ext_vector_type(8))) _Float16 half8;    // 8 f16
typedef __attribute__((ext_vector_type(4))) float floatx4;

// counted-waitcnt pipeline primitives (T4): barrier WITHOUT vmcnt(0) drain
#define ASM_VMCNT(n) asm volatile("s_waitcnt vmcnt(" #n ")" ::: "memory")
#define ASM_LGKM0()  asm volatile("s_waitcnt lgkmcnt(0)" ::: "memory")
#define BAR()        __builtin_amdgcn_s_barrier()

static __device__ __forceinline__ u16 f2bf(float f) {          // RNE f32->bf16
    unsigned u = __float_as_uint(f);
    u += 0x7fffu + ((u >> 16) & 1u);
    return (u16)(u >> 16);
}
static __device__ __forceinline__ float bf2f(u16 s) {
    return __uint_as_float(((unsigned)s) << 16);
}
static __device__ __forceinline__ u16 f2h_bits(float f) {      // RNE f32->f16 bits
    _Float16 h = (_Float16)f;
    u16 u;
    __builtin_memcpy(&u, &h, 2);
    return u;
}
static __device__ __forceinline__ void gl_lds16(const u16* g, u16* l) {
    __builtin_amdgcn_global_load_lds(
        (const __attribute__((address_space(1))) void*)g,
        (__attribute__((address_space(3))) void*)l, 16, 0, 0);
}

// ---------------------------------------------------------------------------
// Fused prologue (1 launch): x -> bf16 hi/lo; qkv_w -> bf16 hi/lo;
// proj_w -> f16 hi/lo; bm table (bias/mask/pad fused, tn-innermost layout).
// ---------------------------------------------------------------------------
#define X4 4816896     // S/4
#define W4 110592
#define P4 36864
#define BM4 49152
__global__ __launch_bounds__(256) void prep(const float* __restrict__ x,
                                            const float* __restrict__ qkv_w,
                                            const float* __restrict__ proj_w,
                                            const float* __restrict__ rel_bias,
                                            const int* __restrict__ rel_coords,
                                            const int* __restrict__ mask,
                                            u16* __restrict__ xbh, u16* __restrict__ xbl,
                                            u16* __restrict__ wbh, u16* __restrict__ wbl,
                                            u16* __restrict__ pfh, u16* __restrict__ pfl,
                                            float* __restrict__ bm) {
    int idx = blockIdx.x * 256 + threadIdx.x;
    if (idx < X4) {
        float4 v = ((const float4*)x)[idx];
        ushort4 h, l;
        h.x = f2bf(v.x); l.x = f2bf(v.x - bf2f(h.x));
        h.y = f2bf(v.y); l.y = f2bf(v.y - bf2f(h.y));
        h.z = f2bf(v.z); l.z = f2bf(v.z - bf2f(h.z));
        h.w = f2bf(v.w); l.w = f2bf(v.w - bf2f(h.w));
        ((ushort4*)xbh)[idx] = h;
        ((ushort4*)xbl)[idx] = l;
    } else if (idx < X4 + W4) {
        int i = idx - X4;
        float4 v = ((const float4*)qkv_w)[i];
        ushort4 h, l;
        h.x = f2bf(v.x); l.x = f2bf(v.x - bf2f(h.x));
        h.y = f2bf(v.y); l.y = f2bf(v.y - bf2f(h.y));
        h.z = f2bf(v.z); l.z = f2bf(v.z - bf2f(h.z));
        h.w = f2bf(v.w); l.w = f2bf(v.w - bf2f(h.w));
        ((ushort4*)wbh)[i] = h;
        ((ushort4*)wbl)[i] = l;
    } else if (idx < X4 + W4 + P4) {
        int i = idx - (X4 + W4);
        float4 v = ((const float4*)proj_w)[i];
        ushort4 h, l;
        h.x = f2h_bits(v.x); l.x = f2h_bits(v.x - (float)(_Float16)v.x);
        h.y = f2h_bits(v.y); l.y = f2h_bits(v.y - (float)(_Float16)v.y);
        h.z = f2h_bits(v.z); l.z = f2h_bits(v.z - (float)(_Float16)v.z);
        h.w = f2h_bits(v.w); l.w = f2h_bits(v.w - (float)(_Float16)v.w);
        ((ushort4*)pfh)[i] = h;
        ((ushort4*)pfl)[i] = l;
    } else if (idx < X4 + W4 + P4 + BM4) {
        int t = idx - (X4 + W4 + P4);
        float4 o;
        float* op = (float*)&o;
#pragma unroll
        for (int i = 0; i < 4; ++i) {
            int j = t * 4 + i;                 // bm flat index
            int e = j & 63;
            int col = (e & 3) * 16 + (e >> 2); // tn*16 + lc
            int row = (j >> 6) & 63;
            int wh_ = j >> 12;                 // 0..47
            int w = wh_ / NH;
            int h = wh_ - w * NH;
            float val = -1.0e30f;
            if (row < LW && col < LW) {
                int ij = row * LW + col;
                val = mask[w * (LW * LW) + ij] ? -1.0e4f
                                               : rel_bias[rel_coords[ij] * NH + h];
            }
            op[i] = val;
        }
        ((float4*)bm)[t] = o;
    }
}

// ---------------------------------------------------------------------------
// QKV GEMM (split-bf16): r3-verified 2-deep dbuf + counted-vmcnt protocol,
// now with 8 WAVES per block (512 threads, wave-tile 64x32) at the same
// 128x128 tile and 64 KB LDS -> 16 waves/CU (was 8): 2x TLP for latency
// cover. Per-wave stage = 4 loads (q/k) or 2 (v); vmcnt counts halved
// accordingly (same queue algebra as r3). q/k (nt<6): 3-term; v: 1-term.
// XCD-chunked grid (3528 = 441*8), n-tile innermost (A-panel L2 reuse).
// ---------------------------------------------------------------------------
__global__ __launch_bounds__(512) void qkv_gemm(const u16* __restrict__ Ah,
                                                const u16* __restrict__ Al,
                                                const u16* __restrict__ Wh,
                                                const u16* __restrict__ Wl,
                                                u32* __restrict__ qp,
                                                u32* __restrict__ kp,
                                                u16* __restrict__ vp) {
    __shared__ u16 As_h[2][128 * 32];
    __shared__ u16 As_l[2][128 * 32];
    __shared__ u16 Bs_h[2][128 * 32];
    __shared__ u16 Bs_l[2][128 * 32];
    const int tid = threadIdx.x;
    const int w = tid >> 6;            // 0..7
    const int lane = tid & 63;
    // grid = 3528 = 441*8; XCD-chunked bijection, n-tile innermost
    const int bid = blockIdx.x;
    const int logical = (bid & 7) * 441 + (bid >> 3);
    const int mt = logical / 9;
    const int nt = logical - mt * 9;
    const int m0 = mt * 128;
    const int n0 = nt * 128;
    const bool vblk = (nt >= 6);
    const int quad = lane >> 4;
    const int lc = lane & 15;
    const int wrow = (w >> 2) << 6;    // 0 or 64
    const int wcol = (w & 3) << 5;     // 0,32,64,96
    const int srow = lane >> 2;
    const int sch = (lane & 3) * 8;

    floatx4 acc[4][2];
#pragma unroll
    for (int a = 0; a < 4; ++a)
#pragma unroll
        for (int b = 0; b < 2; ++b) acc[a][b] = (floatx4){0.f, 0.f, 0.f, 0.f};

    auto stage = [&](int buf, int k0) {   // q/k: 4 loads/wave; v: 2
        const int rb = w * 16;
        const size_t ga = (size_t)(m0 + rb + srow) * CD + k0 + sch;
        const size_t gb = (size_t)(n0 + rb + srow) * CD + k0 + sch;
        const int lof = rb * 32;
        gl_lds16(Ah + ga, As_h[buf] + lof);
        gl_lds16(Wh + gb, Bs_h[buf] + lof);
        if (!vblk) {
            gl_lds16(Al + ga, As_l[buf] + lof);
            gl_lds16(Wl + gb, Bs_l[buf] + lof);
        }
    };

    auto compute = [&](int buf) {
        if (!vblk) {
            short8 af_h[4], af_l[4], bf_h[2], bf_l[2];
#pragma unroll
            for (int t = 0; t < 4; ++t) {
                const int ar = (wrow + t * 16 + lc) * 32 + quad * 8;
                af_h[t] = *(const short8*)(As_h[buf] + ar);
                af_l[t] = *(const short8*)(As_l[buf] + ar);
            }
#pragma unroll
            for (int u = 0; u < 2; ++u) {
                const int br = (wcol + u * 16 + lc) * 32 + quad * 8;
                bf_h[u] = *(const short8*)(Bs_h[buf] + br);
                bf_l[u] = *(const short8*)(Bs_l[buf] + br);
            }
#pragma unroll
            for (int tm = 0; tm < 4; ++tm)
#pragma unroll
                for (int tn = 0; tn < 2; ++tn) {
                    acc[tm][tn] = __builtin_amdgcn_mfma_f32_16x16x32_bf16(af_h[tm], bf_h[tn], acc[tm][tn], 0, 0, 0);
                    acc[tm][tn] = __builtin_amdgcn_mfma_f32_16x16x32_bf16(af_h[tm], bf_l[tn], acc[tm][tn], 0, 0, 0);
                    acc[tm][tn] = __builtin_amdgcn_mfma_f32_16x16x32_bf16(af_l[tm], bf_h[tn], acc[tm][tn], 0, 0, 0);
                }
        } else {
            short8 af_h[4], bf_h[2];
#pragma unroll
            for (int t = 0; t < 4; ++t)
                af_h[t] = *(const short8*)(As_h[buf] + (wrow + t * 16 + lc) * 32 + quad * 8);
#pragma unroll
            for (int u = 0; u < 2; ++u)
                bf_h[u] = *(const short8*)(Bs_h[buf] + (wcol + u * 16 + lc) * 32 + quad * 8);
#pragma unroll
            for (int tm = 0; tm < 4; ++tm)
#pragma unroll
                for (int tn = 0; tn < 2; ++tn)
                    acc[tm][tn] = __builtin_amdgcn_mfma_f32_16x16x32_bf16(af_h[tm], bf_h[tn], acc[tm][tn], 0, 0, 0);
        }
    };

    stage(0, 0);
    stage(1, 32);
    if (!vblk) {
#pragma unroll
        for (int t = 0; t < 12; t += 2) {
            ASM_VMCNT(4); BAR();
            compute(0);
            ASM_LGKM0(); BAR();
            if (t + 2 < 12) { stage(0, (t + 2) * 32); ASM_VMCNT(4); }
            else            { ASM_VMCNT(0); }
            BAR();
            compute(1);
            ASM_LGKM0(); BAR();
            if (t + 2 < 12) stage(1, (t + 3) * 32);
        }
    } else {
#pragma unroll
        for (int t = 0; t < 12; t += 2) {
            ASM_VMCNT(2); BAR();
            compute(0);
            ASM_LGKM0(); BAR();
            if (t + 2 < 12) { stage(0, (t + 2) * 32); ASM_VMCNT(2); }
            else            { ASM_VMCNT(0); }
            BAR();
            compute(1);
            ASM_LGKM0(); BAR();
            if (t + 2 < 12) stage(1, (t + 3) * 32);
        }
    }

    // epilogue: D col = lane&15, row = quad*4 + reg
#pragma unroll
    for (int tn = 0; tn < 2; ++tn) {
        const int nst = n0 + wcol + tn * 16;
        const int t = nst / CD;
        const int rem = nst - t * CD;
        const int h = rem >> 5;
        const int db = (rem & 31) + lc;
#pragma unroll
        for (int tm = 0; tm < 4; ++tm)
#pragma unroll
            for (int r = 0; r < 4; ++r) {
                const int m = m0 + wrow + tm * 16 + quad * 4 + r;
                const int b = m / LW;
                const int l = m - b * LW;
                const size_t o = ((((size_t)b * NH + h) * LW + l) << 5) + db;
                const float vv = acc[tm][tn][r];
                if (t == 2) {
                    vp[o] = f2h_bits(vv);
                } else {
                    const unsigned bits = __float_as_uint(vv);
                    const unsigned hi_high = bits & 0xffff0000u;
                    const u16 lo = f2bf(vv - __uint_as_float(hi_high));
                    const u32 packed = hi_high | (u32)lo;
                    if (t == 0) qp[o] = packed; else kp[o] = packed;
                }
            }
    }
}

// ---------------------------------------------------------------------------
// Proj GEMM (f16 2-term): same r3 protocol, 8 waves (512 thr, wave 64x32).
// Per-wave stage = 3 loads; vmcnt(3). out = A*(Wh+Wl)^T + pb.
// ---------------------------------------------------------------------------
__global__ __launch_bounds__(512) void proj_gemm(const u16* __restrict__ Af,
                                                 const u16* __restrict__ Wfh,
                                                 const u16* __restrict__ Wfl,
                                                 const float* __restrict__ pb,
                                                 float* __restrict__ outF) {
    __shared__ u16 As_f[2][128 * 32];
    __shared__ u16 Bs_h[2][128 * 32];
    __shared__ u16 Bs_l[2][128 * 32];
    const int tid = threadIdx.x;
    const int w = tid >> 6;
    const int lane = tid & 63;
    // grid = 1176 = 147*8; XCD-chunked bijection, n-tile innermost
    const int bid = blockIdx.x;
    const int logical = (bid & 7) * 147 + (bid >> 3);
    const int mt = logical / 3;
    const int nt = logical - mt * 3;
    const int m0 = mt * 128;
    const int n0 = nt * 128;
    const int quad = lane >> 4;
    const int lc = lane & 15;
    const int wrow = (w >> 2) << 6;
    const int wcol = (w & 3) << 5;
    const int srow = lane >> 2;
    const int sch = (lane & 3) * 8;

    floatx4 acc[4][2];
#pragma unroll
    for (int a = 0; a < 4; ++a)
#pragma unroll
        for (int b = 0; b < 2; ++b) acc[a][b] = (floatx4){0.f, 0.f, 0.f, 0.f};

    auto stage = [&](int buf, int k0) {   // 3 loads/wave
        const int rb = w * 16;
        const size_t ga = (size_t)(m0 + rb + srow) * CD + k0 + sch;
        const size_t gb = (size_t)(n0 + rb + srow) * CD + k0 + sch;
        const int lof = rb * 32;
        gl_lds16(Af + ga, As_f[buf] + lof);
        gl_lds16(Wfh + gb, Bs_h[buf] + lof);
        gl_lds16(Wfl + gb, Bs_l[buf] + lof);
    };

    auto compute = [&](int buf) {
        half8 af[4], bh[2], bl[2];
#pragma unroll
        for (int t = 0; t < 4; ++t)
            af[t] = *(const half8*)(As_f[buf] + (wrow + t * 16 + lc) * 32 + quad * 8);
#pragma unroll
        for (int u = 0; u < 2; ++u) {
            const int br = (wcol + u * 16 + lc) * 32 + quad * 8;
            bh[u] = *(const half8*)(Bs_h[buf] + br);
            bl[u] = *(const half8*)(Bs_l[buf] + br);
        }
#pragma unroll
        for (int tm = 0; tm < 4; ++tm)
#pragma unroll
            for (int tn = 0; tn < 2; ++tn) {
                acc[tm][tn] = __builtin_amdgcn_mfma_f32_16x16x32_f16(af[tm], bh[tn], acc[tm][tn], 0, 0, 0);
                acc[tm][tn] = __builtin_amdgcn_mfma_f32_16x16x32_f16(af[tm], bl[tn], acc[tm][tn], 0, 0, 0);
            }
    };

    stage(0, 0);
    stage(1, 32);
#pragma unroll
    for (int t = 0; t < 12; t += 2) {
        ASM_VMCNT(3); BAR();
        compute(0);
        ASM_LGKM0(); BAR();
        if (t + 2 < 12) { stage(0, (t + 2) * 32); ASM_VMCNT(3); }
        else            { ASM_VMCNT(0); }
        BAR();
        compute(1);
        ASM_LGKM0(); BAR();
        if (t + 2 < 12) stage(1, (t + 3) * 32);
    }

#pragma unroll
    for (int tn = 0; tn < 2; ++tn) {
        const int n = n0 + wcol + tn * 16 + lc;
        const float bias = pb[n];
#pragma unroll
        for (int tm = 0; tm < 4; ++tm)
#pragma unroll
            for (int r = 0; r < 4; ++r) {
                const int m = m0 + wrow + tm * 16 + quad * 4 + r;
                outF[(size_t)m * CD + n] = acc[tm][tn][r] + bias;
            }
    }
}

// ---------------------------------------------------------------------------
// MFMA attention: 1 wave per (b,h). q/k packed u32 (hi|lo bf16) from global;
// S = 3-term split-bf16; in-register softmax with DEFERRED 1/sum (P stored
// unnormalized e<=1 in f16; epilogue multiplies by inv in f32).
// Output: single f16, [m][C] layout for the proj GEMM.
// ---------------------------------------------------------------------------
__global__ __launch_bounds__(64) void attn_mfma(const u32* __restrict__ qp,
                                                const u32* __restrict__ kp,
                                                const u16* __restrict__ vh,
                                                const float* __restrict__ bm,
                                                u16* __restrict__ aof) {
    const int bh = blockIdx.x;
    const int b = bh / NH;
    const int h = bh - b * NH;
    const int lane = threadIdx.x;
    const int quad = lane >> 4;
    const int lc = lane & 15;
    __shared__ u16 Vt[32 * 72];
    __shared__ u16 Ps[64 * 72];

    const size_t base = (size_t)bh * (LW * HD);

    short8 aQh[4], aQl[4], bKh[4], bKl[4];
#pragma unroll
    for (int t = 0; t < 4; ++t) {
        int row = t * 16 + lc; if (row > 48) row = 48;
        const size_t o = base + (size_t)row * HD + quad * 8;
        uint4 q0 = *(const uint4*)(qp + o);
        uint4 q1 = *(const uint4*)(qp + o + 4);
        uint4 k0 = *(const uint4*)(kp + o);
        uint4 k1 = *(const uint4*)(kp + o + 4);
        unsigned qv[8] = {q0.x, q0.y, q0.z, q0.w, q1.x, q1.y, q1.z, q1.w};
        unsigned kv[8] = {k0.x, k0.y, k0.z, k0.w, k1.x, k1.y, k1.z, k1.w};
#pragma unroll
        for (int e = 0; e < 8; ++e) {
            aQh[t][e] = (short)(qv[e] >> 16);
            aQl[t][e] = (short)(qv[e] & 0xffffu);
            bKh[t][e] = (short)(kv[e] >> 16);
            bKl[t][e] = (short)(kv[e] & 0xffffu);
        }
    }
    // stage V^T (f16): Vt[d][j] = v[min(j,48)][d]
#pragma unroll
    for (int it = 0; it < 4; ++it) {
        const int idx = lane + it * 64;
        const int j = idx >> 2;
        const int jc = j > 48 ? 48 : j;
        const int ch = (idx & 3) * 8;
        short8 vv = *(const short8*)(vh + base + (size_t)jc * HD + ch);
#pragma unroll
        for (int e = 0; e < 8; ++e) Vt[(ch + e) * 72 + j] = (u16)vv[e];
    }

    floatx4 acc[4][4];
#pragma unroll
    for (int a = 0; a < 4; ++a)
#pragma unroll
        for (int c = 0; c < 4; ++c) acc[a][c] = (floatx4){0.f, 0.f, 0.f, 0.f};
#pragma unroll
    for (int tm = 0; tm < 4; ++tm)
#pragma unroll
        for (int tn = 0; tn < 4; ++tn) {
            acc[tm][tn] = __builtin_amdgcn_mfma_f32_16x16x32_bf16(aQh[tm], bKh[tn], acc[tm][tn], 0, 0, 0);
            acc[tm][tn] = __builtin_amdgcn_mfma_f32_16x16x32_bf16(aQh[tm], bKl[tn], acc[tm][tn], 0, 0, 0);
            acc[tm][tn] = __builtin_amdgcn_mfma_f32_16x16x32_bf16(aQl[tm], bKh[tn], acc[tm][tn], 0, 0, 0);
        }

    float inv_a[16];   // per-(tm,r) 1/sum, fully unrolled static indexing
    const float* bmp = bm + (((size_t)(b & 3) * NH + h) << 12);
#pragma unroll
    for (int tm = 0; tm < 4; ++tm)
#pragma unroll
        for (int r = 0; r < 4; ++r) {
            const int row = tm * 16 + quad * 4 + r;
            const float4 bv = *(const float4*)(bmp + row * 64 + lc * 4);
            const float s0 = fmaf(acc[tm][0][r], SCALE_F, bv.x);
            const float s1 = fmaf(acc[tm][1][r], SCALE_F, bv.y);
            const float s2 = fmaf(acc[tm][2][r], SCALE_F, bv.z);
            const float s3 = fmaf(acc[tm][3][r], SCALE_F, bv.w);
            float mx = fmaxf(fmaxf(s0, s1), fmaxf(s2, s3));
#pragma unroll
            for (int off = 1; off < 16; off <<= 1) mx = fmaxf(mx, __shfl_xor(mx, off));
            const float e0 = __expf(s0 - mx);
            const float e1 = __expf(s1 - mx);
            const float e2 = __expf(s2 - mx);
            const float e3 = __expf(s3 - mx);
            float sum = (e0 + e1) + (e2 + e3);
#pragma unroll
            for (int off = 1; off < 16; off <<= 1) sum += __shfl_xor(sum, off);
            inv_a[tm * 4 + r] = __builtin_amdgcn_rcpf(sum);
            Ps[row * 72 +  0 + lc] = f2h_bits(e0);
            Ps[row * 72 + 16 + lc] = f2h_bits(e1);
            Ps[row * 72 + 32 + lc] = f2h_bits(e2);
            Ps[row * 72 + 48 + lc] = f2h_bits(e3);
        }

    __syncthreads();

    floatx4 o[4][2];
#pragma unroll
    for (int a = 0; a < 4; ++a) { o[a][0] = (floatx4){0.f,0.f,0.f,0.f}; o[a][1] = (floatx4){0.f,0.f,0.f,0.f}; }
#pragma unroll
    for (int ks = 0; ks < 2; ++ks) {
        const half8 bV0 = *(const half8*)(Vt + (lc) * 72 + ks * 32 + quad * 8);
        const half8 bV1 = *(const half8*)(Vt + (16 + lc) * 72 + ks * 32 + quad * 8);
#pragma unroll
        for (int tm = 0; tm < 4; ++tm) {
            const half8 aP = *(const half8*)(Ps + (tm * 16 + lc) * 72 + ks * 32 + quad * 8);
            o[tm][0] = __builtin_amdgcn_mfma_f32_16x16x32_f16(aP, bV0, o[tm][0], 0, 0, 0);
            o[tm][1] = __builtin_amdgcn_mfma_f32_16x16x32_f16(aP, bV1, o[tm][1], 0, 0, 0);
        }
    }
#pragma unroll
    for (int tm = 0; tm < 4; ++tm)
#pragma unroll
        for (int r = 0; r < 4; ++r) {
            const int i = tm * 16 + quad * 4 + r;
            if (i < LW) {
                const float inv = inv_a[tm * 4 + r];
#pragma unroll
                for (int tn = 0; tn < 2; ++tn) {
                    const size_t mm = ((size_t)b * LW + i) * CD + h * HD + tn * 16 + lc;
                    aof[mm] = f2h_bits(o[tm][tn][r] * inv);
                }
            }
        }
}

// ---------------------------------------------------------------------------
extern "C" void kernel_launch(void* const* d_in, const int* in_sizes, int n_in,
                              void* d_out, int out_size, void* d_ws, size_t ws_size,
                              hipStream_t stream) {
    const float* x          = (const float*)d_in[0];
    const int*   mask       = (const int*)d_in[1];
    const float* qkv_w      = (const float*)d_in[2];
    const float* proj_w     = (const float*)d_in[3];
    const float* proj_b     = (const float*)d_in[4];
    const float* rel_bias   = (const float*)d_in[5];
    const int*   rel_coords = (const int*)d_in[6];
    float* out = (float*)d_out;

    const size_t S = (size_t)NUM_B * NH * LW * HD;   // 19,267,584
    // ws (u16 units): xbh S | xbl S | kp 2S | vh S | wbh/wbl | pfh/pfl | bm
    u16* xbh = (u16*)d_ws;
    u16* xbl = xbh + S;
    u32* kp  = (u32*)(xbl + S);           // S u32
    u16* vh  = (u16*)(kp + S);            // S u16
    u16* wbh = vh + S;                    // 442368
    u16* wbl = wbh + 442368;
    u16* pfh = wbl + 442368;              // 147456
    u16* pfl = pfh + 147456;
    float* bm = (float*)(pfl + 147456);   // 196608 floats
    // q packed lives in d_out (S u32 == out_size f32); dead before proj writes
    u32* qp = (u32*)d_out;
    // attn f16 output reuses xbh (x dead after qkv_gemm)
    u16* aof = xbh;

    prep<<<dim3(19584), dim3(256), 0, stream>>>(x, qkv_w, proj_w, rel_bias, rel_coords,
                                                mask, xbh, xbl, wbh, wbl, pfh, pfl, bm);
    qkv_gemm<<<dim3(3528), dim3(512), 0, stream>>>(xbh, xbl, wbh, wbl, qp, kp, vh);
    attn_mfma<<<dim3(NUM_B * NH), dim3(64), 0, stream>>>(qp, kp, vh, bm, aof);
    proj_gemm<<<dim3(1176), dim3(512), 0, stream>>>(aof, pfh, pfl, proj_b, out);
}